// Round 1
// baseline (1557.603 us; speedup 1.0000x reference)
//
#include <hip/hip_runtime.h>
#include <stdint.h>

// ---------- helpers ----------
typedef short short8 __attribute__((ext_vector_type(8)));
typedef float f32x4 __attribute__((ext_vector_type(4)));

__device__ __forceinline__ float bf2f(unsigned int u) {
    union { unsigned int i; float f; } v; v.i = u << 16; return v.f;
}
__device__ __forceinline__ unsigned short f2bf(float f) {
    unsigned int u = __float_as_uint(f);
    u += 0x7fffu + ((u >> 16) & 1u);   // round-to-nearest-even
    return (unsigned short)(u >> 16);
}

// ---------- fp32 -> bf16 convert (vectorized, grid covers n/4 float4s) ----------
__global__ void cvt_f32_bf16(const float* __restrict__ src, unsigned short* __restrict__ dst, int n4) {
    int i = blockIdx.x * blockDim.x + threadIdx.x;
    if (i < n4) {
        float4 v = ((const float4*)src)[i];
        unsigned short r0 = f2bf(v.x), r1 = f2bf(v.y), r2 = f2bf(v.z), r3 = f2bf(v.w);
        unsigned int lo = (unsigned int)r0 | ((unsigned int)r1 << 16);
        unsigned int hi = (unsigned int)r2 | ((unsigned int)r3 << 16);
        ((uint2*)dst)[i] = make_uint2(lo, hi);
    }
}

// ---------- bf16 NT GEMM: C[M,N] = A[M,K] @ B[N,K]^T + bias[N] ----------
// 128x128 tile, BK=64, 256 threads = 4 waves (2x2), each wave 64x64 via 4x4 mfma tiles.
// LDS layout: [kb = k/8][m (0..127)][8 bf16]  -> 16B-contiguous fragments, conflict-free b128.
template<int OUT_BF16>
__global__ __launch_bounds__(256) void gemm_bt(const unsigned short* __restrict__ A,
                                               const unsigned short* __restrict__ Bm,
                                               const float* __restrict__ bias,
                                               void* __restrict__ Cv,
                                               int M, int N, int K)
{
    __shared__ unsigned short As[8 * 128 * 8];
    __shared__ unsigned short Bs[8 * 128 * 8];
    const int tid  = threadIdx.x;
    const int bm   = blockIdx.x, bn = blockIdx.y;
    const int lane = tid & 63, wid = tid >> 6;
    const int wm   = wid >> 1, wn = wid & 1;
    const int quad = lane >> 4, l15 = lane & 15;

    f32x4 acc[4][4];
#pragma unroll
    for (int mt = 0; mt < 4; mt++)
#pragma unroll
        for (int nt = 0; nt < 4; nt++)
            acc[mt][nt] = (f32x4){0.f, 0.f, 0.f, 0.f};

    const int kTiles = K >> 6;
    for (int kt = 0; kt < kTiles; ++kt) {
        __syncthreads();
#pragma unroll
        for (int i = 0; i < 4; i++) {
            int s = tid + i * 256;
            int m = s >> 3, kb = s & 7;
            uint4 va = *(const uint4*)(A  + (size_t)(bm * 128 + m) * K + kt * 64 + kb * 8);
            uint4 vb = *(const uint4*)(Bm + (size_t)(bn * 128 + m) * K + kt * 64 + kb * 8);
            *(uint4*)(As + (kb * 128 + m) * 8) = va;
            *(uint4*)(Bs + (kb * 128 + m) * 8) = vb;
        }
        __syncthreads();
#pragma unroll
        for (int ks = 0; ks < 2; ++ks) {
            short8 af[4], bfr[4];
#pragma unroll
            for (int mt = 0; mt < 4; mt++)
                af[mt] = *(const short8*)(As + ((ks * 4 + quad) * 128 + wm * 64 + mt * 16 + l15) * 8);
#pragma unroll
            for (int nt = 0; nt < 4; nt++)
                bfr[nt] = *(const short8*)(Bs + ((ks * 4 + quad) * 128 + wn * 64 + nt * 16 + l15) * 8);
#pragma unroll
            for (int mt = 0; mt < 4; mt++)
#pragma unroll
                for (int nt = 0; nt < 4; nt++)
                    acc[mt][nt] = __builtin_amdgcn_mfma_f32_16x16x32_bf16(af[mt], bfr[nt], acc[mt][nt], 0, 0, 0);
        }
    }
    // epilogue: D row = quad*4+reg, col = l15  (m89-verified)
    const int row0 = bm * 128 + wm * 64, col0 = bn * 128 + wn * 64;
#pragma unroll
    for (int nt = 0; nt < 4; nt++) {
        int col = col0 + nt * 16 + l15;
        float bv = bias[col];
#pragma unroll
        for (int mt = 0; mt < 4; mt++) {
#pragma unroll
            for (int r = 0; r < 4; r++) {
                int row = row0 + mt * 16 + quad * 4 + r;
                float v = acc[mt][nt][r] + bv;
                if (OUT_BF16) ((unsigned short*)Cv)[(size_t)row * N + col] = f2bf(v);
                else          ((float*)Cv)[(size_t)row * N + col] = v;
            }
        }
    }
}

// ---------- causal flash attention, fp32 vector math ----------
// QKV: (8192, 3072) bf16, cols [0,1024)=Q, [1024,2048)=K, [2048,3072)=V; feature = h*64+d.
// Block = 128 threads (2 waves), each thread owns one query row. Grid: (B*H, T/128).
#define NEG_INF (-1e30f)
__global__ __launch_bounds__(128) void attn_fwd(const unsigned short* __restrict__ QKV,
                                                unsigned short* __restrict__ O)
{
    __shared__ float Ks[64 * 68];   // +4 pad: conflict-free staging writes
    __shared__ float Vs[64 * 68];
    const int tid = threadIdx.x;
    const int bh  = blockIdx.x;           // 0..63
    const int qt  = blockIdx.y;           // 0..15
    const int b   = bh >> 4, h = bh & 15;
    const int qi  = qt * 128 + tid;       // global query index

    float q[64], o[64];
    float m = NEG_INF, l = 0.f;
    const uint4* qp = (const uint4*)(QKV + (size_t)(b * 2048 + qi) * 3072 + h * 64);
#pragma unroll
    for (int i = 0; i < 8; i++) {
        uint4 u = qp[i];
        q[i*8+0] = bf2f(u.x & 0xffffu); q[i*8+1] = bf2f(u.x >> 16);
        q[i*8+2] = bf2f(u.y & 0xffffu); q[i*8+3] = bf2f(u.y >> 16);
        q[i*8+4] = bf2f(u.z & 0xffffu); q[i*8+5] = bf2f(u.z >> 16);
        q[i*8+6] = bf2f(u.w & 0xffffu); q[i*8+7] = bf2f(u.w >> 16);
    }
#pragma unroll
    for (int d = 0; d < 64; d++) o[d] = 0.f;

    const int nTiles = 2 * qt + 2;        // key tiles of 64 covering keys <= qt*128+127
    for (int kt = 0; kt < nTiles; ++kt) {
        __syncthreads();
        {
            int r  = tid & 63;
            int kv = tid >> 6;            // wave0 stages K, wave1 stages V
            const uint4* sp = (const uint4*)(QKV + (size_t)(b * 2048 + kt * 64 + r) * 3072
                                             + 1024 + kv * 1024 + h * 64);
            float* dst = (kv ? Vs : Ks) + r * 68;
#pragma unroll
            for (int i = 0; i < 8; i++) {
                uint4 u = sp[i];
                dst[i*8+0] = bf2f(u.x & 0xffffu); dst[i*8+1] = bf2f(u.x >> 16);
                dst[i*8+2] = bf2f(u.y & 0xffffu); dst[i*8+3] = bf2f(u.y >> 16);
                dst[i*8+4] = bf2f(u.z & 0xffffu); dst[i*8+5] = bf2f(u.z >> 16);
                dst[i*8+6] = bf2f(u.w & 0xffffu); dst[i*8+7] = bf2f(u.w >> 16);
            }
        }
        __syncthreads();
        const int kbase = kt * 64;
#pragma unroll 1
        for (int cc = 0; cc < 8; ++cc) {
            float s[8];
#pragma unroll
            for (int c = 0; c < 8; c++) {
                const float4* kr = (const float4*)(Ks + (cc * 8 + c) * 68);
                float a0 = 0.f, a1 = 0.f, a2 = 0.f, a3 = 0.f;
#pragma unroll
                for (int d4 = 0; d4 < 16; d4++) {
                    float4 kvv = kr[d4];
                    a0 += q[d4*4+0] * kvv.x; a1 += q[d4*4+1] * kvv.y;
                    a2 += q[d4*4+2] * kvv.z; a3 += q[d4*4+3] * kvv.w;
                }
                float sv = ((a0 + a1) + (a2 + a3)) * 0.125f;   // scale = 1/sqrt(64)
                int j = kbase + cc * 8 + c;
                s[c] = (j <= qi) ? sv : NEG_INF;
            }
            float mc = s[0];
#pragma unroll
            for (int c = 1; c < 8; c++) mc = fmaxf(mc, s[c]);
            float mn = fmaxf(m, mc);
            float alpha = __expf(m - mn);
            float ls = 0.f;
#pragma unroll
            for (int c = 0; c < 8; c++) { s[c] = __expf(s[c] - mn); ls += s[c]; }
            l = l * alpha + ls;
            m = mn;
#pragma unroll
            for (int d = 0; d < 64; d++) o[d] *= alpha;
#pragma unroll
            for (int c = 0; c < 8; c++) {
                const float4* vr = (const float4*)(Vs + (cc * 8 + c) * 68);
                float p = s[c];
#pragma unroll
                for (int d4 = 0; d4 < 16; d4++) {
                    float4 vv = vr[d4];
                    o[d4*4+0] += p * vv.x; o[d4*4+1] += p * vv.y;
                    o[d4*4+2] += p * vv.z; o[d4*4+3] += p * vv.w;
                }
            }
        }
    }
    float inv = 1.f / l;
    unsigned short* op = O + (size_t)(b * 2048 + qi) * 1024 + h * 64;
#pragma unroll
    for (int d = 0; d < 64; d++) op[d] = f2bf(o[d] * inv);
}

// ---------- launch ----------
extern "C" void kernel_launch(void* const* d_in, const int* in_sizes, int n_in,
                              void* d_out, int out_size, void* d_ws, size_t ws_size,
                              hipStream_t stream)
{
    const float* x   = (const float*)d_in[0];
    const float* q_w = (const float*)d_in[1];
    const float* q_b = (const float*)d_in[2];
    const float* k_w = (const float*)d_in[3];
    const float* k_b = (const float*)d_in[4];
    const float* v_w = (const float*)d_in[5];
    const float* v_b = (const float*)d_in[6];
    const float* o_w = (const float*)d_in[7];
    const float* o_b = (const float*)d_in[8];
    float* out = (float*)d_out;

    // workspace layout (bf16 elements unless noted); total ~92.3 MB
    unsigned short* Xb   = (unsigned short*)d_ws;        // 8192*1024
    unsigned short* Wqkv = Xb + 8388608;                 // 3072*1024 (q_w|k_w|v_w rows)
    unsigned short* Owb  = Wqkv + 3145728;               // 1024*1024
    float*          bqkv = (float*)(Owb + 1048576);      // 3072 fp32
    unsigned short* QKV  = (unsigned short*)(bqkv + 3072); // 8192*3072
    unsigned short* Abf  = QKV + 25165824;               // 8192*1024

    cvt_f32_bf16<<<8192, 256, 0, stream>>>(x, Xb, 2097152);
    cvt_f32_bf16<<<1024, 256, 0, stream>>>(q_w, Wqkv,            262144);
    cvt_f32_bf16<<<1024, 256, 0, stream>>>(k_w, Wqkv + 1048576,  262144);
    cvt_f32_bf16<<<1024, 256, 0, stream>>>(v_w, Wqkv + 2097152,  262144);
    cvt_f32_bf16<<<1024, 256, 0, stream>>>(o_w, Owb,             262144);
    hipMemcpyAsync(bqkv,        q_b, 1024 * sizeof(float), hipMemcpyDeviceToDevice, stream);
    hipMemcpyAsync(bqkv + 1024, k_b, 1024 * sizeof(float), hipMemcpyDeviceToDevice, stream);
    hipMemcpyAsync(bqkv + 2048, v_b, 1024 * sizeof(float), hipMemcpyDeviceToDevice, stream);

    gemm_bt<1><<<dim3(64, 24), 256, 0, stream>>>(Xb, Wqkv, bqkv, QKV, 8192, 3072, 1024);
    attn_fwd<<<dim3(64, 16), 128, 0, stream>>>(QKV, Abf);
    gemm_bt<0><<<dim3(64, 8), 256, 0, stream>>>(Abf, Owb, o_b, out, 8192, 1024, 1024);
}

// Round 2
// 441.827 us; speedup vs baseline: 3.5254x; 3.5254x over previous
//
#include <hip/hip_runtime.h>
#include <stdint.h>

// ---------- helpers ----------
typedef short short8 __attribute__((ext_vector_type(8)));
typedef float f32x4 __attribute__((ext_vector_type(4)));

__device__ __forceinline__ float bf2f(unsigned int u) {
    union { unsigned int i; float f; } v; v.i = u << 16; return v.f;
}
__device__ __forceinline__ unsigned short f2bf(float f) {
    unsigned int u = __float_as_uint(f);
    u += 0x7fffu + ((u >> 16) & 1u);   // round-to-nearest-even
    return (unsigned short)(u >> 16);
}

// ---------- fp32 -> bf16 convert ----------
__global__ void cvt_f32_bf16(const float* __restrict__ src, unsigned short* __restrict__ dst, int n4) {
    int i = blockIdx.x * blockDim.x + threadIdx.x;
    if (i < n4) {
        float4 v = ((const float4*)src)[i];
        unsigned short r0 = f2bf(v.x), r1 = f2bf(v.y), r2 = f2bf(v.z), r3 = f2bf(v.w);
        unsigned int lo = (unsigned int)r0 | ((unsigned int)r1 << 16);
        unsigned int hi = (unsigned int)r2 | ((unsigned int)r3 << 16);
        ((uint2*)dst)[i] = make_uint2(lo, hi);
    }
}

// ---------- bf16 NT GEMM: C[M,N] = A[M,K] @ B[N,K]^T + bias[N] ----------
template<int OUT_BF16>
__global__ __launch_bounds__(256) void gemm_bt(const unsigned short* __restrict__ A,
                                               const unsigned short* __restrict__ Bm,
                                               const float* __restrict__ bias,
                                               void* __restrict__ Cv,
                                               int M, int N, int K)
{
    __shared__ unsigned short As[8 * 128 * 8];
    __shared__ unsigned short Bs[8 * 128 * 8];
    const int tid  = threadIdx.x;
    const int bm   = blockIdx.x, bn = blockIdx.y;
    const int lane = tid & 63, wid = tid >> 6;
    const int wm   = wid >> 1, wn = wid & 1;
    const int quad = lane >> 4, l15 = lane & 15;

    f32x4 acc[4][4];
#pragma unroll
    for (int mt = 0; mt < 4; mt++)
#pragma unroll
        for (int nt = 0; nt < 4; nt++)
            acc[mt][nt] = (f32x4){0.f, 0.f, 0.f, 0.f};

    const int kTiles = K >> 6;
    for (int kt = 0; kt < kTiles; ++kt) {
        __syncthreads();
#pragma unroll
        for (int i = 0; i < 4; i++) {
            int s = tid + i * 256;
            int m = s >> 3, kb = s & 7;
            uint4 va = *(const uint4*)(A  + (size_t)(bm * 128 + m) * K + kt * 64 + kb * 8);
            uint4 vb = *(const uint4*)(Bm + (size_t)(bn * 128 + m) * K + kt * 64 + kb * 8);
            *(uint4*)(As + (kb * 128 + m) * 8) = va;
            *(uint4*)(Bs + (kb * 128 + m) * 8) = vb;
        }
        __syncthreads();
#pragma unroll
        for (int ks = 0; ks < 2; ++ks) {
            short8 af[4], bfr[4];
#pragma unroll
            for (int mt = 0; mt < 4; mt++)
                af[mt] = *(const short8*)(As + ((ks * 4 + quad) * 128 + wm * 64 + mt * 16 + l15) * 8);
#pragma unroll
            for (int nt = 0; nt < 4; nt++)
                bfr[nt] = *(const short8*)(Bs + ((ks * 4 + quad) * 128 + wn * 64 + nt * 16 + l15) * 8);
#pragma unroll
            for (int mt = 0; mt < 4; mt++)
#pragma unroll
                for (int nt = 0; nt < 4; nt++)
                    acc[mt][nt] = __builtin_amdgcn_mfma_f32_16x16x32_bf16(af[mt], bfr[nt], acc[mt][nt], 0, 0, 0);
        }
    }
    const int row0 = bm * 128 + wm * 64, col0 = bn * 128 + wn * 64;
#pragma unroll
    for (int nt = 0; nt < 4; nt++) {
        int col = col0 + nt * 16 + l15;
        float bv = bias[col];
#pragma unroll
        for (int mt = 0; mt < 4; mt++) {
#pragma unroll
            for (int r = 0; r < 4; r++) {
                int row = row0 + mt * 16 + quad * 4 + r;
                float v = acc[mt][nt][r] + bv;
                if (OUT_BF16) ((unsigned short*)Cv)[(size_t)row * N + col] = f2bf(v);
                else          ((float*)Cv)[(size_t)row * N + col] = v;
            }
        }
    }
}

// ---------- MFMA causal flash attention ----------
// QKV: (8192, 3072) bf16, cols [0,1024)=Q, [1024,2048)=K, [2048,3072)=V; feature = h*64+d.
// Block = 256 thr (4 waves). Grid (B*H=64, T/64=32). Block owns 64 query rows; wave owns 16.
// Per 64-key tile: K staged row-major [key][d] stride 72; V staged TRANSPOSED [d][key^swz] stride 72.
// S = Q@K^T via mfma (A=Q regs, B=Ks), online softmax in C-layout, P -> LDS, O += P@V (B=Vt).
#define NEG_INF (-1e30f)
__global__ __launch_bounds__(256) void attn_mfma(const unsigned short* __restrict__ QKV,
                                                 unsigned short* __restrict__ O)
{
    __shared__ __align__(16) unsigned short Ks[64 * 72];
    __shared__ __align__(16) unsigned short Vt[64 * 72];
    __shared__ __align__(16) unsigned short Ps[4 * 16 * 72];
    const int tid  = threadIdx.x;
    const int lane = tid & 63, w = tid >> 6;
    const int quad = lane >> 4, l15 = lane & 15;
    const int bh   = blockIdx.x;
    const int b    = bh >> 4, h = bh & 15;
    const int qt   = (int)gridDim.y - 1 - (int)blockIdx.y;   // longest blocks dispatch first

    // Q fragments in registers: A[m = l15][k = quad*8+j], k-step kk covers d = kk*32..+31
    const int q_row = qt * 64 + w * 16 + l15;
    short8 qf[2];
#pragma unroll
    for (int kk = 0; kk < 2; kk++)
        qf[kk] = *(const short8*)(QKV + (size_t)(b * 2048 + q_row) * 3072 + h * 64 + kk * 32 + quad * 8);

    f32x4 oacc[4];
#pragma unroll
    for (int nt = 0; nt < 4; nt++) oacc[nt] = (f32x4){0.f, 0.f, 0.f, 0.f};
    float mrow[4], lrow[4];
#pragma unroll
    for (int r = 0; r < 4; r++) { mrow[r] = NEG_INF; lrow[r] = 0.f; }

    for (int kt = 0; kt <= qt; ++kt) {
        __syncthreads();   // protect Ks/Vt/Ps reuse from previous iteration
        // ---- stage K and V^T ----
        {
            const unsigned short* Kb = QKV + (size_t)(b * 2048 + kt * 64) * 3072 + 1024 + h * 64;
            const unsigned short* Vb = Kb + 1024;
#pragma unroll
            for (int i = 0; i < 2; i++) {
                int s = tid + i * 256;            // 0..511
                int key = s >> 3, c8 = s & 7;     // key row, d-chunk of 8
                uint4 kv4 = *(const uint4*)(Kb + (size_t)key * 3072 + c8 * 8);
                *(uint4*)(Ks + (key * 72 + c8 * 8)) = kv4;
                uint4 vv4 = *(const uint4*)(Vb + (size_t)key * 3072 + c8 * 8);
                const unsigned short* vp = (const unsigned short*)&vv4;
#pragma unroll
                for (int j = 0; j < 8; j++) {
                    int d = c8 * 8 + j;
                    int keysw = key ^ (((d >> 3) & 3) << 4);   // swizzle: spread transpose-write banks
                    Vt[d * 72 + keysw] = vp[j];
                }
            }
        }
        __syncthreads();

        // ---- S = Q @ K^T (per-wave 16 rows x 64 keys) ----
        f32x4 sacc[4];
#pragma unroll
        for (int nt = 0; nt < 4; nt++) sacc[nt] = (f32x4){0.f, 0.f, 0.f, 0.f};
#pragma unroll
        for (int kk = 0; kk < 2; kk++) {
#pragma unroll
            for (int nt = 0; nt < 4; nt++) {
                short8 kf = *(const short8*)(Ks + (nt * 16 + l15) * 72 + kk * 32 + quad * 8);
                sacc[nt] = __builtin_amdgcn_mfma_f32_16x16x32_bf16(qf[kk], kf, sacc[nt], 0, 0, 0);
            }
        }

        // ---- online softmax (C layout: row = quad*4+r, col = nt*16+l15) ----
        float sv[4][4];
        const bool diag = (kt == qt);
#pragma unroll
        for (int nt = 0; nt < 4; nt++) {
#pragma unroll
            for (int r = 0; r < 4; r++) {
                float v = sacc[nt][r] * 0.125f;
                if (diag && (nt * 16 + l15 > w * 16 + quad * 4 + r)) v = NEG_INF;
                sv[nt][r] = v;
            }
        }
        float mx[4], alpha[4], ls[4];
#pragma unroll
        for (int r = 0; r < 4; r++) {
            float m0 = fmaxf(fmaxf(sv[0][r], sv[1][r]), fmaxf(sv[2][r], sv[3][r]));
            m0 = fmaxf(m0, __shfl_xor(m0, 1));
            m0 = fmaxf(m0, __shfl_xor(m0, 2));
            m0 = fmaxf(m0, __shfl_xor(m0, 4));
            m0 = fmaxf(m0, __shfl_xor(m0, 8));
            mx[r] = m0;
            float mn = fmaxf(mrow[r], m0);
            alpha[r] = __expf(mrow[r] - mn);
            mrow[r] = mn;
            ls[r] = 0.f;
        }
#pragma unroll
        for (int nt = 0; nt < 4; nt++)
#pragma unroll
            for (int r = 0; r < 4; r++) {
                float p = __expf(sv[nt][r] - mrow[r]);
                sv[nt][r] = p;
                ls[r] += p;
            }
#pragma unroll
        for (int r = 0; r < 4; r++) {
            float s0 = ls[r];
            s0 += __shfl_xor(s0, 1);
            s0 += __shfl_xor(s0, 2);
            s0 += __shfl_xor(s0, 4);
            s0 += __shfl_xor(s0, 8);
            lrow[r] = lrow[r] * alpha[r] + s0;
        }
#pragma unroll
        for (int nt = 0; nt < 4; nt++)
#pragma unroll
            for (int r = 0; r < 4; r++)
                oacc[nt][r] *= alpha[r];

        // ---- P (C layout) -> LDS (A layout source) ----
        unsigned short* Pw = Ps + w * 16 * 72;
#pragma unroll
        for (int nt = 0; nt < 4; nt++)
#pragma unroll
            for (int r = 0; r < 4; r++)
                Pw[(quad * 4 + r) * 72 + nt * 16 + l15] = f2bf(sv[nt][r]);
        __syncthreads();

        // ---- O += P @ V : A = Ps[m=l15][k=key], B = Vt[n=d][k=key] ----
#pragma unroll
        for (int kk = 0; kk < 2; kk++) {
            short8 pf = *(const short8*)(Pw + l15 * 72 + kk * 32 + quad * 8);
#pragma unroll
            for (int nt = 0; nt < 4; nt++) {
                int d = nt * 16 + l15;
                int kbase = (kk * 32 + quad * 8) ^ (((d >> 3) & 3) << 4);   // un-swizzle
                short8 vf = *(const short8*)(Vt + d * 72 + kbase);
                oacc[nt] = __builtin_amdgcn_mfma_f32_16x16x32_bf16(pf, vf, oacc[nt], 0, 0, 0);
            }
        }
    }

    // ---- epilogue: O /= l, write bf16 ----
#pragma unroll
    for (int r = 0; r < 4; r++) {
        float inv = 1.f / lrow[r];
        int row = qt * 64 + w * 16 + quad * 4 + r;
        unsigned short* op = O + (size_t)(b * 2048 + row) * 1024 + h * 64;
#pragma unroll
        for (int nt = 0; nt < 4; nt++)
            op[nt * 16 + l15] = f2bf(oacc[nt][r] * inv);
    }
}

// ---------- launch ----------
extern "C" void kernel_launch(void* const* d_in, const int* in_sizes, int n_in,
                              void* d_out, int out_size, void* d_ws, size_t ws_size,
                              hipStream_t stream)
{
    const float* x   = (const float*)d_in[0];
    const float* q_w = (const float*)d_in[1];
    const float* q_b = (const float*)d_in[2];
    const float* k_w = (const float*)d_in[3];
    const float* k_b = (const float*)d_in[4];
    const float* v_w = (const float*)d_in[5];
    const float* v_b = (const float*)d_in[6];
    const float* o_w = (const float*)d_in[7];
    const float* o_b = (const float*)d_in[8];
    float* out = (float*)d_out;

    unsigned short* Xb   = (unsigned short*)d_ws;        // 8192*1024
    unsigned short* Wqkv = Xb + 8388608;                 // 3072*1024
    unsigned short* Owb  = Wqkv + 3145728;               // 1024*1024
    float*          bqkv = (float*)(Owb + 1048576);      // 3072 fp32
    unsigned short* QKV  = (unsigned short*)(bqkv + 3072); // 8192*3072
    unsigned short* Abf  = QKV + 25165824;               // 8192*1024

    cvt_f32_bf16<<<8192, 256, 0, stream>>>(x, Xb, 2097152);
    cvt_f32_bf16<<<1024, 256, 0, stream>>>(q_w, Wqkv,            262144);
    cvt_f32_bf16<<<1024, 256, 0, stream>>>(k_w, Wqkv + 1048576,  262144);
    cvt_f32_bf16<<<1024, 256, 0, stream>>>(v_w, Wqkv + 2097152,  262144);
    cvt_f32_bf16<<<1024, 256, 0, stream>>>(o_w, Owb,             262144);
    hipMemcpyAsync(bqkv,        q_b, 1024 * sizeof(float), hipMemcpyDeviceToDevice, stream);
    hipMemcpyAsync(bqkv + 1024, k_b, 1024 * sizeof(float), hipMemcpyDeviceToDevice, stream);
    hipMemcpyAsync(bqkv + 2048, v_b, 1024 * sizeof(float), hipMemcpyDeviceToDevice, stream);

    gemm_bt<1><<<dim3(64, 24), 256, 0, stream>>>(Xb, Wqkv, bqkv, QKV, 8192, 3072, 1024);
    attn_mfma<<<dim3(64, 32), 256, 0, stream>>>(QKV, Abf);
    gemm_bt<0><<<dim3(64, 8), 256, 0, stream>>>(Abf, Owb, o_b, out, 8192, 1024, 1024);
}

// Round 3
// 380.652 us; speedup vs baseline: 4.0919x; 1.1607x over previous
//
#include <hip/hip_runtime.h>
#include <stdint.h>

typedef short short8 __attribute__((ext_vector_type(8)));
typedef float f32x4 __attribute__((ext_vector_type(4)));

__device__ __forceinline__ unsigned short f2bf(float f) {
    unsigned int u = __float_as_uint(f);
    u += 0x7fffu + ((u >> 16) & 1u);   // round-to-nearest-even
    return (unsigned short)(u >> 16);
}

// async global->LDS, 16B per lane; lds base must be wave-uniform (HW adds lane*16)
__device__ __forceinline__ void gld_lds16(const unsigned short* g, unsigned short* l) {
    __builtin_amdgcn_global_load_lds((const __attribute__((address_space(1))) unsigned int*)g,
                                     (__attribute__((address_space(3))) unsigned int*)l,
                                     16, 0, 0);
}

// ---------- fp32 -> bf16 convert ----------
__global__ void cvt_f32_bf16(const float* __restrict__ src, unsigned short* __restrict__ dst, int n4) {
    int i = blockIdx.x * blockDim.x + threadIdx.x;
    if (i < n4) {
        float4 v = ((const float4*)src)[i];
        unsigned int lo = (unsigned int)f2bf(v.x) | ((unsigned int)f2bf(v.y) << 16);
        unsigned int hi = (unsigned int)f2bf(v.z) | ((unsigned int)f2bf(v.w) << 16);
        ((uint2*)dst)[i] = make_uint2(lo, hi);
    }
}

// ---------- bf16 NT GEMM: C[M,N] = A[M,K] @ B[N,K]^T + bias[N] ----------
// 128x128 tile, BK=64, 4 waves, global_load_lds(16) staging.
// LDS: row-major [m][64] with granule swizzle g_slot = g ^ (m&7): DMA dest lane-contiguous,
// source stays in one 128B line per 8 lanes, frag reads 2-way bank (free).
// MODE 0: C0 = fp32 [M][N].  MODE 1 (QKV): col<2048 -> bf16 QK[row*2048+col]; col>=2048 -> Vt transposed.
template<int MODE>
__global__ __launch_bounds__(256) void gemm_bt(const unsigned short* __restrict__ A,
                                               const unsigned short* __restrict__ Bm,
                                               const float* __restrict__ bias,
                                               void* __restrict__ C0,
                                               unsigned short* __restrict__ VtOut,
                                               int M, int N, int K)
{
    __shared__ __align__(16) unsigned short As[128 * 64];
    __shared__ __align__(16) unsigned short Bs[128 * 64];
    const int tid  = threadIdx.x;
    const int bm   = blockIdx.x, bn = blockIdx.y;
    const int lane = tid & 63, w = tid >> 6;
    const int wm   = w >> 1, wn = w & 1;
    const int quad = lane >> 4, l15 = lane & 15;

    f32x4 acc[4][4];
#pragma unroll
    for (int mt = 0; mt < 4; mt++)
#pragma unroll
        for (int nt = 0; nt < 4; nt++)
            acc[mt][nt] = (f32x4){0.f, 0.f, 0.f, 0.f};

    const int kTiles = K >> 6;
    for (int kt = 0; kt < kTiles; ++kt) {
        __syncthreads();
#pragma unroll
        for (int i = 0; i < 4; i++) {
            int G  = i * 256 + tid;          // global granule slot 0..1023
            int m  = G >> 3, g = G & 7;
            int gs = g ^ (m & 7);            // source granule (xor swizzle)
            int Gb = i * 256 + (w << 6);     // wave-uniform dest base slot
            gld_lds16(A  + (size_t)(bm * 128 + m) * K + kt * 64 + gs * 8, &As[Gb * 8]);
            gld_lds16(Bm + (size_t)(bn * 128 + m) * K + kt * 64 + gs * 8, &Bs[Gb * 8]);
        }
        __syncthreads();   // compiler drains vmcnt here
#pragma unroll
        for (int ks = 0; ks < 2; ++ks) {
            short8 af[4], bfr[4];
#pragma unroll
            for (int mt = 0; mt < 4; mt++) {
                int m = wm * 64 + mt * 16 + l15;
                af[mt] = *(const short8*)&As[m * 64 + (((ks * 4 + quad) ^ (l15 & 7)) << 3)];
            }
#pragma unroll
            for (int nt = 0; nt < 4; nt++) {
                int n = wn * 64 + nt * 16 + l15;
                bfr[nt] = *(const short8*)&Bs[n * 64 + (((ks * 4 + quad) ^ (l15 & 7)) << 3)];
            }
#pragma unroll
            for (int mt = 0; mt < 4; mt++)
#pragma unroll
                for (int nt = 0; nt < 4; nt++)
                    acc[mt][nt] = __builtin_amdgcn_mfma_f32_16x16x32_bf16(af[mt], bfr[nt], acc[mt][nt], 0, 0, 0);
        }
    }
    // epilogue: D row = quad*4+reg, col = l15
    const int row0 = bm * 128 + wm * 64, col0 = bn * 128 + wn * 64;
#pragma unroll
    for (int nt = 0; nt < 4; nt++) {
        int col = col0 + nt * 16 + l15;
        float bv = bias[col];
#pragma unroll
        for (int mt = 0; mt < 4; mt++) {
            if (MODE == 1 && col >= 2048) {
                // V: write transposed Vt[(b*1024 + (col-2048))*2048 + t], 4 consecutive t -> 8B store
                int row = row0 + mt * 16 + quad * 4;
                int b = row >> 11, t = row & 2047;
                ushort4 pk;
                pk.x = f2bf(acc[mt][nt][0] + bv);
                pk.y = f2bf(acc[mt][nt][1] + bv);
                pk.z = f2bf(acc[mt][nt][2] + bv);
                pk.w = f2bf(acc[mt][nt][3] + bv);
                *(ushort4*)(VtOut + (size_t)(b * 1024 + (col - 2048)) * 2048 + t) = pk;
            } else {
#pragma unroll
                for (int r = 0; r < 4; r++) {
                    int row = row0 + mt * 16 + quad * 4 + r;
                    float v = acc[mt][nt][r] + bv;
                    if (MODE == 1) ((unsigned short*)C0)[(size_t)row * 2048 + col] = f2bf(v);
                    else           ((float*)C0)[(size_t)row * N + col] = v;
                }
            }
        }
    }
}

// ---------- MFMA causal flash attention, no barriers ----------
// QK: (8192, 2048) bf16 rows = (b,t), cols [0,1024)=Q, [1024,2048)=K (feature h*64+d).
// Vt: [b*16+h][d][t] bf16 (written transposed by the QKV GEMM).
// Block 256 = 4 waves; wave owns 32 q rows (2 m-tiles). Grid (64 bh, 16 qtiles).
// K/V fragments load DIRECTLY from global (b128). LDS only for P transpose (wave-private).
#define NEG_RAW (-1e30f)
__global__ __launch_bounds__(256) void attn_mfma(const unsigned short* __restrict__ QK,
                                                 const unsigned short* __restrict__ Vt,
                                                 unsigned short* __restrict__ O)
{
    __shared__ __align__(16) unsigned short Ps[4 * 32 * 72];
    const int tid  = threadIdx.x;
    const int lane = tid & 63, w = tid >> 6;
    const int quad = lane >> 4, l15 = lane & 15;
    const int bh   = blockIdx.x;
    const int b    = bh >> 4, h = bh & 15;
    const int qt   = (int)gridDim.y - 1 - (int)blockIdx.y;   // longest first
    const int qbase = qt * 128 + w * 32;

    const unsigned short* Qp = QK + (size_t)(b * 2048) * 2048 + h * 64;
    const unsigned short* Kp = Qp + 1024;
    const unsigned short* Vp = Vt + (size_t)(bh * 64) * 2048;
    unsigned short* Pw = Ps + w * 32 * 72;

    short8 qf[2][2];
#pragma unroll
    for (int mt = 0; mt < 2; mt++)
#pragma unroll
        for (int kk = 0; kk < 2; kk++)
            qf[mt][kk] = *(const short8*)(Qp + (size_t)(qbase + mt * 16 + l15) * 2048 + kk * 32 + quad * 8);

    short8 ones;
#pragma unroll
    for (int j = 0; j < 8; j++) ones[j] = (short)0x3F80;   // bf16 1.0

    f32x4 oacc[2][4], lacc[2];
    float mrow[2][4];
#pragma unroll
    for (int mt = 0; mt < 2; mt++) {
        lacc[mt] = (f32x4){0.f, 0.f, 0.f, 0.f};
#pragma unroll
        for (int nt = 0; nt < 4; nt++) oacc[mt][nt] = (f32x4){0.f, 0.f, 0.f, 0.f};
#pragma unroll
        for (int r = 0; r < 4; r++) mrow[mt][r] = NEG_RAW;
    }

    const int ktmax = (qbase + 31) >> 6;     // wave stops when keys exceed its rows
    for (int kt = 0; kt <= ktmax; ++kt) {
        const int kbase = kt * 64;
        // ---- S = Q @ K^T : K fragments direct from global ----
        f32x4 sacc[2][4];
#pragma unroll
        for (int mt = 0; mt < 2; mt++)
#pragma unroll
            for (int nt = 0; nt < 4; nt++) sacc[mt][nt] = (f32x4){0.f, 0.f, 0.f, 0.f};
#pragma unroll
        for (int kk = 0; kk < 2; kk++) {
#pragma unroll
            for (int nt = 0; nt < 4; nt++) {
                short8 kf = *(const short8*)(Kp + (size_t)(kbase + nt * 16 + l15) * 2048 + kk * 32 + quad * 8);
                sacc[0][nt] = __builtin_amdgcn_mfma_f32_16x16x32_bf16(qf[0][kk], kf, sacc[0][nt], 0, 0, 0);
                sacc[1][nt] = __builtin_amdgcn_mfma_f32_16x16x32_bf16(qf[1][kk], kf, sacc[1][nt], 0, 0, 0);
            }
        }
        // ---- online softmax per m-tile (C layout: row=quad*4+r, col=nt*16+l15) ----
#pragma unroll
        for (int mt = 0; mt < 2; mt++) {
            if (kbase + 63 > qbase + mt * 16) {     // tile straddles diagonal for this m-tile
#pragma unroll
                for (int nt = 0; nt < 4; nt++)
#pragma unroll
                    for (int r = 0; r < 4; r++)
                        if (kbase + nt * 16 + l15 > qbase + mt * 16 + quad * 4 + r)
                            sacc[mt][nt][r] = NEG_RAW;
            }
            float alpha[4];
#pragma unroll
            for (int r = 0; r < 4; r++) {
                float v = fmaxf(fmaxf(sacc[mt][0][r], sacc[mt][1][r]),
                                fmaxf(sacc[mt][2][r], sacc[mt][3][r]));
                v = fmaxf(v, __shfl_xor(v, 1));
                v = fmaxf(v, __shfl_xor(v, 2));
                v = fmaxf(v, __shfl_xor(v, 4));
                v = fmaxf(v, __shfl_xor(v, 8));
                float mn = fmaxf(mrow[mt][r], v);
                alpha[r] = __expf((mrow[mt][r] - mn) * 0.125f);
                mrow[mt][r] = mn;
            }
            // P -> LDS, stride 72, col ^ (quad*16) swizzle: conflict-free writes, aligned b128 reads
            unsigned short* Pm = Pw + mt * 16 * 72;
#pragma unroll
            for (int nt = 0; nt < 4; nt++)
#pragma unroll
                for (int r = 0; r < 4; r++) {
                    float p = __expf((sacc[mt][nt][r] - mrow[mt][r]) * 0.125f);
                    Pm[(quad * 4 + r) * 72 + ((nt * 16 + l15) ^ (quad << 4))] = f2bf(p);
                }
#pragma unroll
            for (int nt = 0; nt < 4; nt++)
#pragma unroll
                for (int r = 0; r < 4; r++)
                    oacc[mt][nt][r] *= alpha[r];
#pragma unroll
            for (int r = 0; r < 4; r++) lacc[mt][r] *= alpha[r];
        }
        // ---- O += P @ V : P from LDS (A-frag), V fragments direct from global Vt ----
        const int q2 = (l15 >> 2) & 3;                       // row-quad of A-frag row = l15
#pragma unroll
        for (int kv = 0; kv < 2; kv++) {
            int colsw = (kv * 32 + quad * 8) ^ (q2 << 4);    // un-swizzle
            short8 pf0 = *(const short8*)&Pw[l15 * 72 + colsw];
            short8 pf1 = *(const short8*)&Pw[(16 + l15) * 72 + colsw];
            lacc[0] = __builtin_amdgcn_mfma_f32_16x16x32_bf16(pf0, ones, lacc[0], 0, 0, 0);
            lacc[1] = __builtin_amdgcn_mfma_f32_16x16x32_bf16(pf1, ones, lacc[1], 0, 0, 0);
#pragma unroll
            for (int nt = 0; nt < 4; nt++) {
                short8 vf = *(const short8*)(Vp + (size_t)(nt * 16 + l15) * 2048 + kbase + kv * 32 + quad * 8);
                oacc[0][nt] = __builtin_amdgcn_mfma_f32_16x16x32_bf16(pf0, vf, oacc[0][nt], 0, 0, 0);
                oacc[1][nt] = __builtin_amdgcn_mfma_f32_16x16x32_bf16(pf1, vf, oacc[1][nt], 0, 0, 0);
            }
        }
    }
    // ---- epilogue ----
#pragma unroll
    for (int mt = 0; mt < 2; mt++)
#pragma unroll
        for (int r = 0; r < 4; r++) {
            float inv = 1.f / lacc[mt][r];
            int row = qbase + mt * 16 + quad * 4 + r;
            unsigned short* op = O + (size_t)(b * 2048 + row) * 1024 + h * 64;
#pragma unroll
            for (int nt = 0; nt < 4; nt++)
                op[nt * 16 + l15] = f2bf(oacc[mt][nt][r] * inv);
        }
}

// ---------- launch ----------
extern "C" void kernel_launch(void* const* d_in, const int* in_sizes, int n_in,
                              void* d_out, int out_size, void* d_ws, size_t ws_size,
                              hipStream_t stream)
{
    const float* x   = (const float*)d_in[0];
    const float* q_w = (const float*)d_in[1];
    const float* q_b = (const float*)d_in[2];
    const float* k_w = (const float*)d_in[3];
    const float* k_b = (const float*)d_in[4];
    const float* v_w = (const float*)d_in[5];
    const float* v_b = (const float*)d_in[6];
    const float* o_w = (const float*)d_in[7];
    const float* o_b = (const float*)d_in[8];
    float* out = (float*)d_out;

    unsigned short* Xb   = (unsigned short*)d_ws;          // 8192*1024
    unsigned short* Wqkv = Xb + 8388608;                   // 3072*1024
    unsigned short* Owb  = Wqkv + 3145728;                 // 1024*1024
    float*          bqkv = (float*)(Owb + 1048576);        // 3072 fp32
    unsigned short* QK   = (unsigned short*)(bqkv + 3072); // 8192*2048
    unsigned short* Vtg  = QK + 16777216;                  // 64*64*2048 (transposed V)
    unsigned short* Abf  = Vtg + 8388608;                  // 8192*1024

    cvt_f32_bf16<<<8192, 256, 0, stream>>>(x, Xb, 2097152);
    cvt_f32_bf16<<<1024, 256, 0, stream>>>(q_w, Wqkv,           262144);
    cvt_f32_bf16<<<1024, 256, 0, stream>>>(k_w, Wqkv + 1048576, 262144);
    cvt_f32_bf16<<<1024, 256, 0, stream>>>(v_w, Wqkv + 2097152, 262144);
    cvt_f32_bf16<<<1024, 256, 0, stream>>>(o_w, Owb,            262144);
    hipMemcpyAsync(bqkv,        q_b, 1024 * sizeof(float), hipMemcpyDeviceToDevice, stream);
    hipMemcpyAsync(bqkv + 1024, k_b, 1024 * sizeof(float), hipMemcpyDeviceToDevice, stream);
    hipMemcpyAsync(bqkv + 2048, v_b, 1024 * sizeof(float), hipMemcpyDeviceToDevice, stream);

    gemm_bt<1><<<dim3(64, 24), 256, 0, stream>>>(Xb, Wqkv, bqkv, QK, Vtg, 8192, 3072, 1024);
    attn_mfma<<<dim3(64, 16), 256, 0, stream>>>(QK, Vtg, Abf);
    gemm_bt<0><<<dim3(64, 8), 256, 0, stream>>>(Abf, Owb, o_b, out, nullptr, 8192, 1024, 1024);
}

// Round 4
// 353.271 us; speedup vs baseline: 4.4091x; 1.0775x over previous
//
#include <hip/hip_runtime.h>
#include <stdint.h>

typedef short short8 __attribute__((ext_vector_type(8)));
typedef float f32x4 __attribute__((ext_vector_type(4)));

__device__ __forceinline__ unsigned short f2bf(float f) {
    unsigned int u = __float_as_uint(f);
    u += 0x7fffu + ((u >> 16) & 1u);   // round-to-nearest-even
    return (unsigned short)(u >> 16);
}

// async global->LDS, 16B per lane; lds base must be wave-uniform (HW adds lane*16)
__device__ __forceinline__ void gld_lds16(const unsigned short* g, unsigned short* l) {
    __builtin_amdgcn_global_load_lds((const __attribute__((address_space(1))) unsigned int*)g,
                                     (__attribute__((address_space(3))) unsigned int*)l,
                                     16, 0, 0);
}

// ---------- fp32 -> bf16 convert ----------
__global__ void cvt_f32_bf16(const float* __restrict__ src, unsigned short* __restrict__ dst, int n4) {
    int i = blockIdx.x * blockDim.x + threadIdx.x;
    if (i < n4) {
        float4 v = ((const float4*)src)[i];
        unsigned int lo = (unsigned int)f2bf(v.x) | ((unsigned int)f2bf(v.y) << 16);
        unsigned int hi = (unsigned int)f2bf(v.z) | ((unsigned int)f2bf(v.w) << 16);
        ((uint2*)dst)[i] = make_uint2(lo, hi);
    }
}

// Q pre-scale: fold attn scale (1/8) and log2(e) into Q so attn softmax uses exp2 directly.
#define QSCL 0.18033688011112042f

// ---------- bf16 NT GEMM: C[M,N] = A[M,K] @ B[N,K]^T + bias[N] ----------
// 128x128 tile, BK=64, 4 waves, global_load_lds(16) staging, xor-swizzled LDS.
// MODE 0: C0 = fp32 [M][N].
// MODE 1 (QKV): col<1024 -> bf16 Q (pre-scaled by QSCL); col<2048 -> bf16 K; col>=2048 -> Vt transposed.
template<int MODE>
__global__ __launch_bounds__(256) void gemm_bt(const unsigned short* __restrict__ A,
                                               const unsigned short* __restrict__ Bm,
                                               const float* __restrict__ bias,
                                               void* __restrict__ C0,
                                               unsigned short* __restrict__ VtOut,
                                               int M, int N, int K)
{
    __shared__ __align__(16) unsigned short As[128 * 64];
    __shared__ __align__(16) unsigned short Bs[128 * 64];
    const int tid  = threadIdx.x;
    const int bm   = blockIdx.x, bn = blockIdx.y;
    const int lane = tid & 63, w = tid >> 6;
    const int wm   = w >> 1, wn = w & 1;
    const int quad = lane >> 4, l15 = lane & 15;

    f32x4 acc[4][4];
#pragma unroll
    for (int mt = 0; mt < 4; mt++)
#pragma unroll
        for (int nt = 0; nt < 4; nt++)
            acc[mt][nt] = (f32x4){0.f, 0.f, 0.f, 0.f};

    const int kTiles = K >> 6;
    for (int kt = 0; kt < kTiles; ++kt) {
        __syncthreads();
#pragma unroll
        for (int i = 0; i < 4; i++) {
            int G  = i * 256 + tid;
            int m  = G >> 3, g = G & 7;
            int gs = g ^ (m & 7);
            int Gb = i * 256 + (w << 6);
            gld_lds16(A  + (size_t)(bm * 128 + m) * K + kt * 64 + gs * 8, &As[Gb * 8]);
            gld_lds16(Bm + (size_t)(bn * 128 + m) * K + kt * 64 + gs * 8, &Bs[Gb * 8]);
        }
        __syncthreads();
#pragma unroll
        for (int ks = 0; ks < 2; ++ks) {
            short8 af[4], bfr[4];
#pragma unroll
            for (int mt = 0; mt < 4; mt++) {
                int m = wm * 64 + mt * 16 + l15;
                af[mt] = *(const short8*)&As[m * 64 + (((ks * 4 + quad) ^ (l15 & 7)) << 3)];
            }
#pragma unroll
            for (int nt = 0; nt < 4; nt++) {
                int n = wn * 64 + nt * 16 + l15;
                bfr[nt] = *(const short8*)&Bs[n * 64 + (((ks * 4 + quad) ^ (l15 & 7)) << 3)];
            }
#pragma unroll
            for (int mt = 0; mt < 4; mt++)
#pragma unroll
                for (int nt = 0; nt < 4; nt++)
                    acc[mt][nt] = __builtin_amdgcn_mfma_f32_16x16x32_bf16(af[mt], bfr[nt], acc[mt][nt], 0, 0, 0);
        }
    }
    // epilogue: D row = quad*4+reg, col = l15
    const int row0 = bm * 128 + wm * 64, col0 = bn * 128 + wn * 64;
#pragma unroll
    for (int nt = 0; nt < 4; nt++) {
        int col = col0 + nt * 16 + l15;
        float bv = bias[col];
#pragma unroll
        for (int mt = 0; mt < 4; mt++) {
            if (MODE == 1 && col >= 2048) {
                // V: write transposed Vt[(b*1024 + (col-2048))*2048 + t]
                int row = row0 + mt * 16 + quad * 4;
                int b = row >> 11, t = row & 2047;
                ushort4 pk;
                pk.x = f2bf(acc[mt][nt][0] + bv);
                pk.y = f2bf(acc[mt][nt][1] + bv);
                pk.z = f2bf(acc[mt][nt][2] + bv);
                pk.w = f2bf(acc[mt][nt][3] + bv);
                *(ushort4*)(VtOut + (size_t)(b * 1024 + (col - 2048)) * 2048 + t) = pk;
            } else {
#pragma unroll
                for (int r = 0; r < 4; r++) {
                    int row = row0 + mt * 16 + quad * 4 + r;
                    float v = acc[mt][nt][r] + bv;
                    if (MODE == 1) {
                        if (col < 1024) v *= QSCL;
                        ((unsigned short*)C0)[(size_t)row * 2048 + col] = f2bf(v);
                    } else {
                        ((float*)C0)[(size_t)row * N + col] = v;
                    }
                }
            }
        }
    }
}

// ---------- MFMA causal flash attention, no barriers, S^T formulation ----------
// QK: (8192, 2048) bf16 rows = (b,t), cols [0,1024)=Q (pre-scaled), [1024,2048)=K.
// Vt: [b*16+h][d][t] bf16. Block 256 = 4 waves; wave owns 32 q rows. Grid (64 bh, 16 qtiles).
// S^T = K@Q^T (C rows = keys): row-max is lane-local + 2 shuffles, P packs to b64 writes.
#define NEG_RAW (-1e30f)
__global__ __launch_bounds__(256) void attn_mfma(const unsigned short* __restrict__ QK,
                                                 const unsigned short* __restrict__ Vt,
                                                 unsigned short* __restrict__ O)
{
    __shared__ __align__(16) unsigned short Ps[4 * 32 * 72];
    const int tid  = threadIdx.x;
    const int lane = tid & 63, w = tid >> 6;
    const int quad = lane >> 4, l15 = lane & 15;
    const int bh   = blockIdx.x;
    const int b    = bh >> 4, h = bh & 15;
    const int qt   = (int)gridDim.y - 1 - (int)blockIdx.y;   // longest first
    const int qbase = qt * 128 + w * 32;

    const unsigned short* Qp = QK + (size_t)(b * 2048) * 2048 + h * 64;
    const unsigned short* Kp = Qp + 1024;
    const unsigned short* Vp = Vt + (size_t)(bh * 64) * 2048;
    unsigned short* Pw = Ps + w * 32 * 72;

    // Q fragments (B-operand for S^T): [n = q = l15][k = d = quad*8+j]
    short8 qf[2][2];
#pragma unroll
    for (int mt = 0; mt < 2; mt++)
#pragma unroll
        for (int kk = 0; kk < 2; kk++)
            qf[mt][kk] = *(const short8*)(Qp + (size_t)(qbase + mt * 16 + l15) * 2048 + kk * 32 + quad * 8);

    short8 ones;
#pragma unroll
    for (int j = 0; j < 8; j++) ones[j] = (short)0x3F80;   // bf16 1.0

    f32x4 oacc[2][4], lacc[2];
    float mrow[2] = {NEG_RAW, NEG_RAW};
#pragma unroll
    for (int mt = 0; mt < 2; mt++) {
        lacc[mt] = (f32x4){0.f, 0.f, 0.f, 0.f};
#pragma unroll
        for (int nt = 0; nt < 4; nt++) oacc[mt][nt] = (f32x4){0.f, 0.f, 0.f, 0.f};
    }

    const int ktmax = (qbase + 31) >> 6;
    for (int kt = 0; kt <= ktmax; ++kt) {
        const int kbase = kt * 64;
        // ---- S^T = K @ Q^T : C[m=key][n=q], K fragments direct from global ----
        f32x4 sacc[2][4];
#pragma unroll
        for (int mt = 0; mt < 2; mt++)
#pragma unroll
            for (int nt = 0; nt < 4; nt++) sacc[mt][nt] = (f32x4){0.f, 0.f, 0.f, 0.f};
#pragma unroll
        for (int kk = 0; kk < 2; kk++) {
#pragma unroll
            for (int nt = 0; nt < 4; nt++) {
                short8 kf = *(const short8*)(Kp + (size_t)(kbase + nt * 16 + l15) * 2048 + kk * 32 + quad * 8);
                sacc[0][nt] = __builtin_amdgcn_mfma_f32_16x16x32_bf16(kf, qf[0][kk], sacc[0][nt], 0, 0, 0);
                sacc[1][nt] = __builtin_amdgcn_mfma_f32_16x16x32_bf16(kf, qf[1][kk], sacc[1][nt], 0, 0, 0);
            }
        }
        // ---- mask (diagonal tiles): key = kbase+nt*16+quad*4+r, q = qbase+mt*16+l15 ----
        float alpha[2];
#pragma unroll
        for (int mt = 0; mt < 2; mt++) {
            const int qg = qbase + mt * 16 + l15;
            if (kbase + 63 > qbase + mt * 16) {
#pragma unroll
                for (int nt = 0; nt < 4; nt++)
#pragma unroll
                    for (int r = 0; r < 4; r++)
                        if (kbase + nt * 16 + quad * 4 + r > qg)
                            sacc[mt][nt][r] = NEG_RAW;
            }
            // ---- row max: lane-local over 16, butterfly over quad bits ----
            float mloc = sacc[mt][0][0];
#pragma unroll
            for (int nt = 0; nt < 4; nt++)
#pragma unroll
                for (int r = 0; r < 4; r++) mloc = fmaxf(mloc, sacc[mt][nt][r]);
            mloc = fmaxf(mloc, __shfl_xor(mloc, 16));
            mloc = fmaxf(mloc, __shfl_xor(mloc, 32));
            float mnew = fmaxf(mrow[mt], mloc);
            alpha[mt] = __builtin_exp2f(mrow[mt] - mnew);
            mrow[mt] = mnew;
            // ---- P = exp2(S^T - m), pack 4 consecutive keys -> b64 write ----
#pragma unroll
            for (int nt = 0; nt < 4; nt++) {
                float p0 = __builtin_exp2f(sacc[mt][nt][0] - mnew);
                float p1 = __builtin_exp2f(sacc[mt][nt][1] - mnew);
                float p2 = __builtin_exp2f(sacc[mt][nt][2] - mnew);
                float p3 = __builtin_exp2f(sacc[mt][nt][3] - mnew);
                unsigned int lo = __builtin_amdgcn_perm(__float_as_uint(p1), __float_as_uint(p0), 0x07060302u);
                unsigned int hi = __builtin_amdgcn_perm(__float_as_uint(p3), __float_as_uint(p2), 0x07060302u);
                *(uint2*)&Pw[(mt * 16 + l15) * 72 + nt * 16 + quad * 4] = make_uint2(lo, hi);
            }
        }
        // ---- rescale O,l by alpha (transport alpha to C-layout via bpermute) ----
#pragma unroll
        for (int mt = 0; mt < 2; mt++) {
#pragma unroll
            for (int r = 0; r < 4; r++) {
                int src = (lane & 48) + ((lane >> 4) << 2) + r;   // lane with l15 = quad*4+r
                float aC = __shfl(alpha[mt], src);
#pragma unroll
                for (int nt = 0; nt < 4; nt++) oacc[mt][nt][r] *= aC;
                lacc[mt][r] *= aC;
            }
        }
        // ---- O += P @ V : P from LDS (A-frag), V direct from global Vt ----
#pragma unroll
        for (int kv = 0; kv < 2; kv++) {
            short8 pf0 = *(const short8*)&Pw[l15 * 72 + kv * 32 + quad * 8];
            short8 pf1 = *(const short8*)&Pw[(16 + l15) * 72 + kv * 32 + quad * 8];
            lacc[0] = __builtin_amdgcn_mfma_f32_16x16x32_bf16(pf0, ones, lacc[0], 0, 0, 0);
            lacc[1] = __builtin_amdgcn_mfma_f32_16x16x32_bf16(pf1, ones, lacc[1], 0, 0, 0);
#pragma unroll
            for (int nt = 0; nt < 4; nt++) {
                short8 vf = *(const short8*)(Vp + (size_t)(nt * 16 + l15) * 2048 + kbase + kv * 32 + quad * 8);
                oacc[0][nt] = __builtin_amdgcn_mfma_f32_16x16x32_bf16(pf0, vf, oacc[0][nt], 0, 0, 0);
                oacc[1][nt] = __builtin_amdgcn_mfma_f32_16x16x32_bf16(pf1, vf, oacc[1][nt], 0, 0, 0);
            }
        }
    }
    // ---- epilogue ----
#pragma unroll
    for (int mt = 0; mt < 2; mt++)
#pragma unroll
        for (int r = 0; r < 4; r++) {
            float inv = 1.f / lacc[mt][r];
            int row = qbase + mt * 16 + quad * 4 + r;
            unsigned short* op = O + (size_t)(b * 2048 + row) * 1024 + h * 64;
#pragma unroll
            for (int nt = 0; nt < 4; nt++)
                op[nt * 16 + l15] = f2bf(oacc[mt][nt][r] * inv);
        }
}

// ---------- launch ----------
extern "C" void kernel_launch(void* const* d_in, const int* in_sizes, int n_in,
                              void* d_out, int out_size, void* d_ws, size_t ws_size,
                              hipStream_t stream)
{
    const float* x   = (const float*)d_in[0];
    const float* q_w = (const float*)d_in[1];
    const float* q_b = (const float*)d_in[2];
    const float* k_w = (const float*)d_in[3];
    const float* k_b = (const float*)d_in[4];
    const float* v_w = (const float*)d_in[5];
    const float* v_b = (const float*)d_in[6];
    const float* o_w = (const float*)d_in[7];
    const float* o_b = (const float*)d_in[8];
    float* out = (float*)d_out;

    unsigned short* Xb   = (unsigned short*)d_ws;          // 8192*1024
    unsigned short* Wqkv = Xb + 8388608;                   // 3072*1024
    unsigned short* Owb  = Wqkv + 3145728;                 // 1024*1024
    float*          bqkv = (float*)(Owb + 1048576);        // 3072 fp32
    unsigned short* QK   = (unsigned short*)(bqkv + 3072); // 8192*2048
    unsigned short* Vtg  = QK + 16777216;                  // 64*64*2048 (transposed V)
    unsigned short* Abf  = Vtg + 8388608;                  // 8192*1024

    cvt_f32_bf16<<<8192, 256, 0, stream>>>(x, Xb, 2097152);
    cvt_f32_bf16<<<1024, 256, 0, stream>>>(q_w, Wqkv,           262144);
    cvt_f32_bf16<<<1024, 256, 0, stream>>>(k_w, Wqkv + 1048576, 262144);
    cvt_f32_bf16<<<1024, 256, 0, stream>>>(v_w, Wqkv + 2097152, 262144);
    cvt_f32_bf16<<<1024, 256, 0, stream>>>(o_w, Owb,            262144);
    hipMemcpyAsync(bqkv,        q_b, 1024 * sizeof(float), hipMemcpyDeviceToDevice, stream);
    hipMemcpyAsync(bqkv + 1024, k_b, 1024 * sizeof(float), hipMemcpyDeviceToDevice, stream);
    hipMemcpyAsync(bqkv + 2048, v_b, 1024 * sizeof(float), hipMemcpyDeviceToDevice, stream);

    gemm_bt<1><<<dim3(64, 24), 256, 0, stream>>>(Xb, Wqkv, bqkv, QK, Vtg, 8192, 3072, 1024);
    attn_mfma<<<dim3(64, 16), 256, 0, stream>>>(QK, Vtg, Abf);
    gemm_bt<0><<<dim3(64, 8), 256, 0, stream>>>(Abf, Owb, o_b, out, nullptr, 8192, 1024, 1024);
}